// Round 4
// baseline (480.722 us; speedup 1.0000x reference)
//
#include <hip/hip_runtime.h>
#include <cstdint>
#include <cstddef>

#define NS 512
#define NT 384
#define CZ 128

typedef __bf16 bf16x8 __attribute__((ext_vector_type(8)));
typedef __bf16 bf16x4 __attribute__((ext_vector_type(4)));
typedef float floatx16 __attribute__((ext_vector_type(16)));

// Workspace layouts (bf16 element units):
//   A_t[rb(96)][kc(64)][r(128)][e(8)]   panel = 65536 elems (128 rows, k=s)
//   B_t[pb(48)][kc(64)][r(256)][e(8)]   panel = 131072 elems
//   WT [e(128)][k(1024)]  k = (c>>4)*512 + d*16 + (c&15)
// k index = s;  kc = s>>3, e = s&7.  A-row m = i*32+c, B-row n = j*32+d.
// These layouts make each lane's MFMA fragment contiguous in global memory,
// so opm_gemm loads fragments DIRECTLY from L2 — no LDS staging, no main-loop
// barriers.

// ---------------------------------------------------------------------------
// WT[e][k]: coalesced read of Wout, scattered write (absorbed by L2).
// ---------------------------------------------------------------------------
__global__ __launch_bounds__(256) void prep_wout(const float* __restrict__ Wout,
                                                 __bf16* __restrict__ WT) {
  const int idx = blockIdx.x * 256 + threadIdx.x;  // 131072
  const int cd = idx >> 7, e = idx & 127;
  const int c = cd >> 5, d = cd & 31;
  const int kk = (c >> 4) * 512 + d * 16 + (c & 15);
  WT[(size_t)e * 1024 + kk] = (__bf16)Wout[idx];
}

// ---------------------------------------------------------------------------
__global__ __launch_bounds__(256) void prep_norm(const float* __restrict__ mask,
                                                 float* __restrict__ rnorm) {
  __shared__ float mi[512];
  const int i = blockIdx.x, t = threadIdx.x;
  mi[t]       = mask[(size_t)t * NT + i];
  mi[t + 256] = mask[(size_t)(t + 256) * NT + i];
  __syncthreads();
  for (int j = t; j < NT; j += 256) {
    float acc = 0.f;
#pragma unroll 4
    for (int s = 0; s < NS; ++s) acc += mi[s] * mask[(size_t)s * NT + j];
    rnorm[(size_t)i * NT + j] = 1.0f / (acc + 0.001f);
  }
}

// ---------------------------------------------------------------------------
// LN + projections, writing the tiled layouts. One wave per (i, 64-s chunk).
// ---------------------------------------------------------------------------
__global__ __launch_bounds__(64) void ln_proj(const float* __restrict__ feat,
                                              const float* __restrict__ mask,
                                              const float* __restrict__ gamma,
                                              const float* __restrict__ beta,
                                              const float* __restrict__ Wa,
                                              const float* __restrict__ Wb,
                                              __bf16* __restrict__ Abf,
                                              __bf16* __restrict__ Bbf) {
  __shared__ float tile[64][65];
  __shared__ __bf16 T[32 * 72];  // transpose buffer, row stride 72 (bank-safe)
  const int bid = blockIdx.x;    // 3072
  const int i = bid >> 3;
  const int s0 = (bid & 7) << 6;
  const int lane = threadIdx.x;
  const int l31 = lane & 31, lh = lane >> 5;

  const int rsub = lane >> 4, cb = (lane & 15) * 4;
#pragma unroll
  for (int rr = 0; rr < 16; ++rr) {
    const int row = rr * 4 + rsub;
    const float4 v = *(const float4*)(feat + ((size_t)(s0 + row) * NT + i) * 64 + cb);
    tile[row][cb] = v.x; tile[row][cb + 1] = v.y;
    tile[row][cb + 2] = v.z; tile[row][cb + 3] = v.w;
  }
  __syncthreads();

  float x[64];
#pragma unroll
  for (int k = 0; k < 64; ++k) x[k] = tile[lane][k];  // lane = s-row

  float mu = 0.f;
#pragma unroll
  for (int k = 0; k < 64; ++k) mu += x[k];
  mu *= (1.0f / 64.0f);
  float var = 0.f;
#pragma unroll
  for (int k = 0; k < 64; ++k) { const float d = x[k] - mu; var += d * d; }
  var *= (1.0f / 64.0f);
  const float rstd = rsqrtf(var + 1e-5f);
#pragma unroll
  for (int k = 0; k < 64; ++k)
    x[k] = (x[k] - mu) * rstd * gamma[k] + beta[k];

  const float mv = mask[(size_t)(s0 + lane) * NT + i];

  // ---- projection A ----
  float acc[32];
#pragma unroll
  for (int c = 0; c < 32; ++c) acc[c] = 0.f;
#pragma unroll 8
  for (int k = 0; k < 64; ++k) {
    const float mk = x[k];
#pragma unroll
    for (int c = 0; c < 32; ++c) acc[c] = fmaf(mk, Wa[k * 32 + c], acc[c]);
  }
#pragma unroll
  for (int c = 0; c < 32; ++c) T[c * 72 + lane] = (__bf16)(acc[c] * mv);
  __syncthreads();
  {
    __bf16* dst = Abf + (size_t)(i >> 2) * 65536 + (size_t)(s0 >> 3) * 1024 +
                  (size_t)((i & 3) * 32) * 8;
#pragma unroll
    for (int q = 0; q < 4; ++q) {
      const bf16x8 v = *(const bf16x8*)(T + l31 * 72 + (q * 2 + lh) * 8);
      *(bf16x8*)(dst + (size_t)(q * 2 + lh) * 1024 + l31 * 8) = v;
    }
  }
  __syncthreads();

  // ---- projection B ----
#pragma unroll
  for (int c = 0; c < 32; ++c) acc[c] = 0.f;
#pragma unroll 8
  for (int k = 0; k < 64; ++k) {
    const float mk = x[k];
#pragma unroll
    for (int c = 0; c < 32; ++c) acc[c] = fmaf(mk, Wb[k * 32 + c], acc[c]);
  }
#pragma unroll
  for (int c = 0; c < 32; ++c) T[c * 72 + lane] = (__bf16)(acc[c] * mv);
  __syncthreads();
  {
    __bf16* dst = Bbf + (size_t)(i >> 3) * 131072 + (size_t)(s0 >> 3) * 2048 +
                  (size_t)((i & 7) * 32) * 8;
#pragma unroll
    for (int q = 0; q < 4; ++q) {
      const bf16x8 v = *(const bf16x8*)(T + l31 * 72 + (q * 2 + lh) * 8);
      *(bf16x8*)(dst + (size_t)(q * 2 + lh) * 2048 + l31 * 8) = v;
    }
  }
}

// ---------------------------------------------------------------------------
// Fused GEMM. Block 128x256, 4 waves (2x2), wave 64x128 (2x4 frags 32x32x16).
// MFMA fragments loaded DIRECTLY from global (L2) — no LDS, no barriers in
// the K-loop. Ping-pong register prefetch one kt (64 k-elems) ahead.
// Epilogue: 2 rounds over c-halves via LDS P (32 pairs x 512 cd, padded);
// second GEMM vs WT + bias + norm. Only 3 barriers in the whole kernel.
// ---------------------------------------------------------------------------
__global__ __launch_bounds__(256, 2) void opm_gemm(const __bf16* __restrict__ A,
                                                   const __bf16* __restrict__ B,
                                                   const __bf16* __restrict__ WT,
                                                   const float* __restrict__ bout,
                                                   const float* __restrict__ rnorm,
                                                   float* __restrict__ out) {
  __shared__ __align__(16) __bf16 smem[20736];  // P: addr(p,d,c') = p*648+d*20+c'

  const int t = threadIdx.x, lane = t & 63, wid = t >> 6;
  const int wm = wid & 1, wn = wid >> 1;
  const int l31 = lane & 31, lh = lane >> 5;

  // 4x4 supertile swizzle for L2 locality (grid 4608 = 96 bm x 48 bn)
  const int sq = blockIdx.x >> 4, r4 = blockIdx.x & 15;
  const int bm = (sq % 24) * 4 + (r4 & 3);
  const int bn = (sq / 24) * 4 + (r4 >> 2);

  // Per-lane fragment base pointers (contiguous bf16x8 per lane by layout).
  const __bf16* pA = A + (size_t)bm * 65536 + (size_t)lh * 1024 + (wm * 64 + l31) * 8;
  const __bf16* pB = B + (size_t)bn * 131072 + (size_t)lh * 2048 + (wn * 128 + l31) * 8;

  floatx16 acc[2][4];
#pragma unroll
  for (int fm = 0; fm < 2; ++fm)
#pragma unroll
    for (int fn = 0; fn < 4; ++fn)
#pragma unroll
      for (int q = 0; q < 16; ++q) acc[fm][fn][q] = 0.f;

  bf16x8 fa[2][2][2], fb[2][2][4];  // [buf][ks][frag]

#define LOADKT(kt, b)                                                         \
  {                                                                           \
    _Pragma("unroll")                                                         \
    for (int ks = 0; ks < 2; ++ks) {                                          \
      _Pragma("unroll")                                                       \
      for (int fm = 0; fm < 2; ++fm)                                          \
        fa[b][ks][fm] =                                                       \
            *(const bf16x8*)(pA + (kt) * 4096 + ks * 2048 + fm * 256);        \
      _Pragma("unroll")                                                       \
      for (int fn = 0; fn < 4; ++fn)                                          \
        fb[b][ks][fn] =                                                       \
            *(const bf16x8*)(pB + (kt) * 8192 + ks * 4096 + fn * 256);        \
    }                                                                         \
  }

  LOADKT(0, 0);
#pragma unroll 2
  for (int kt = 0; kt < 16; ++kt) {
    const int b = kt & 1;
    if (kt < 15) LOADKT(kt + 1, b ^ 1);
#pragma unroll
    for (int ks = 0; ks < 2; ++ks)
#pragma unroll
      for (int fm = 0; fm < 2; ++fm)
#pragma unroll
        for (int fn = 0; fn < 4; ++fn)
          acc[fm][fn] = __builtin_amdgcn_mfma_f32_32x32x16_bf16(
              fa[b][ks][fm], fb[b][ks][fn], acc[fm][fn], 0, 0, 0);
  }
#undef LOADKT

  // ---- epilogue: 2 rounds over c-halves ----
  floatx16 z;
#pragma unroll
  for (int q = 0; q < 16; ++q) z[q] = 0.f;
  const int e = wid * 32 + l31;

#pragma unroll
  for (int round = 0; round < 2; ++round) {
    // scatter regs r = round*8 + qp*4 + j  (c = 16*round + 8*qp + 4*lh + j)
#pragma unroll
    for (int fm = 0; fm < 2; ++fm)
#pragma unroll
      for (int fn = 0; fn < 4; ++fn) {
        const int p = (wm * 2 + fm) * 8 + wn * 4 + fn;
        __bf16* base = smem + p * 648 + l31 * 20 + lh * 4;
#pragma unroll
        for (int qp = 0; qp < 2; ++qp) {
          bf16x4 v;
#pragma unroll
          for (int j = 0; j < 4; ++j)
            v[j] = (__bf16)acc[fm][fn][round * 8 + qp * 4 + j];
          *(bf16x4*)(base + qp * 8) = v;
        }
      }
    __syncthreads();
    // GEMM2: z[p][e] += P_half[p][k] * WT[e][round*512 + k], K=512
    const __bf16* wrow = WT + (size_t)e * 1024 + round * 512 + lh * 8;
    const __bf16* prow = smem + l31 * 648 + lh * 8;
#pragma unroll 8
    for (int ks = 0; ks < 32; ++ks) {
      const bf16x8 pa = *(const bf16x8*)(prow + ks * 20);
      const bf16x8 wb = *(const bf16x8*)(wrow + ks * 16);
      z = __builtin_amdgcn_mfma_f32_32x32x16_bf16(pa, wb, z, 0, 0, 0);
    }
    if (round == 0) __syncthreads();  // before round-1 scatter overwrites P
  }

  // out[i][j][e] = (z + bout[e]) * rnorm[i][j]
  const float be = bout[e];
#pragma unroll
  for (int r = 0; r < 16; ++r) {
    const int p = (r & 3) + 8 * (r >> 2) + 4 * lh;
    const int i = bm * 4 + (p >> 3), j = bn * 8 + (p & 7);
    const float rn = rnorm[(size_t)i * NT + j];
    out[((size_t)i * NT + j) * CZ + e] = (z[r] + be) * rn;
  }
}

// ---------------------------------------------------------------------------
extern "C" void kernel_launch(void* const* d_in, const int* in_sizes, int n_in,
                              void* d_out, int out_size, void* d_ws, size_t ws_size,
                              hipStream_t stream) {
  const float* feat  = (const float*)d_in[0];
  const float* mask  = (const float*)d_in[1];
  const float* gamma = (const float*)d_in[2];
  const float* beta  = (const float*)d_in[3];
  const float* Wa    = (const float*)d_in[4];
  const float* Wb    = (const float*)d_in[5];
  const float* Wout  = (const float*)d_in[6];
  const float* bout  = (const float*)d_in[7];
  float* out = (float*)d_out;

  char* ws = (char*)d_ws;
  const size_t AB_BYTES = (size_t)96 * 65536 * sizeof(__bf16);  // 12,582,912
  __bf16* Abf = (__bf16*)(ws);
  __bf16* Bbf = (__bf16*)(ws + AB_BYTES);
  __bf16* WT  = (__bf16*)(ws + 2 * AB_BYTES);
  float* rnorm = (float*)(ws + 2 * AB_BYTES + (size_t)CZ * 1024 * sizeof(__bf16));

  prep_wout<<<512, 256, 0, stream>>>(Wout, WT);
  prep_norm<<<NT, 256, 0, stream>>>(mask, rnorm);
  ln_proj<<<NT * (NS / 64), 64, 0, stream>>>(feat, mask, gamma, beta, Wa, Wb, Abf, Bbf);
  opm_gemm<<<96 * 48, 256, 0, stream>>>(Abf, Bbf, WT, bout, rnorm, out);
}